// Round 1
// baseline (782.195 us; speedup 1.0000x reference)
//
#include <hip/hip_runtime.h>
#include <math.h>

#define BATCH 16384
#define B6 (BATCH*6)
#define DT 0.01f

__device__ __constant__ float c_LOWER[6]  = {-6.28f,-6.28f,-3.14f,-6.28f,-6.28f,-6.28f};
__device__ __constant__ float c_UPPER[6]  = { 6.28f, 6.28f, 3.14f, 6.28f, 6.28f, 6.28f};
__device__ __constant__ float c_EFFORT[6] = {150.0f,150.0f,150.0f,28.0f,28.0f,28.0f};
__device__ __constant__ int   c_ROWOFF[6] = {0,1,3,6,10,15};

__device__ __forceinline__ float sp_f(float z){ return fmaxf(z,0.0f) + log1pf(expf(-fabsf(z))); }
__device__ __forceinline__ float sig_f(float z){ return 1.0f/(1.0f+expf(-z)); }

__device__ __forceinline__ void fma16(float w, const float* __restrict__ src,
                                      float4& a0, float4& a1, float4& a2, float4& a3){
  const float4* p = reinterpret_cast<const float4*>(src);
  float4 h;
  h = p[0]; a0.x=fmaf(w,h.x,a0.x); a0.y=fmaf(w,h.y,a0.y); a0.z=fmaf(w,h.z,a0.z); a0.w=fmaf(w,h.w,a0.w);
  h = p[1]; a1.x=fmaf(w,h.x,a1.x); a1.y=fmaf(w,h.y,a1.y); a1.z=fmaf(w,h.z,a1.z); a1.w=fmaf(w,h.w,a1.w);
  h = p[2]; a2.x=fmaf(w,h.x,a2.x); a2.y=fmaf(w,h.y,a2.y); a2.z=fmaf(w,h.z,a2.z); a2.w=fmaf(w,h.w,a2.w);
  h = p[3]; a3.x=fmaf(w,h.x,a3.x); a3.y=fmaf(w,h.y,a3.y); a3.z=fmaf(w,h.z,a3.z); a3.w=fmaf(w,h.w,a3.w);
}

// softplus+sigmoid of 16 accs -> two LDS rows
__device__ __forceinline__ void act_store(float* __restrict__ hdst, float* __restrict__ sdst,
                                          float4 a0, float4 a1, float4 a2, float4 a3){
  float4 zz[4] = {a0,a1,a2,a3};
  #pragma unroll
  for (int k=0;k<4;k++){
    float4 z = zz[k];
    float4 h, s;
    h.x=sp_f(z.x); h.y=sp_f(z.y); h.z=sp_f(z.z); h.w=sp_f(z.w);
    s.x=sig_f(z.x); s.y=sig_f(z.y); s.z=sig_f(z.z); s.w=sig_f(z.w);
    reinterpret_cast<float4*>(hdst)[k] = h;
    reinterpret_cast<float4*>(sdst)[k] = s;
  }
}

// dst = acc * ssrc (elementwise over 16)
__device__ __forceinline__ void mulstore16(const float* __restrict__ ssrc, float* __restrict__ dst,
                                           float4 a0, float4 a1, float4 a2, float4 a3){
  const float4* ps = reinterpret_cast<const float4*>(ssrc);
  float4* pd = reinterpret_cast<float4*>(dst);
  float4 zz[4]={a0,a1,a2,a3};
  #pragma unroll
  for (int k=0;k<4;k++){
    float4 s=ps[k], z=zz[k];
    pd[k] = make_float4(z.x*s.x, z.y*s.y, z.z*s.z, z.w*s.w);
  }
}

// ---------------- init: transpose weights, zero viol ----------------
__global__ void __launch_bounds__(256) k_init(
    const float* __restrict__ W1L, const float* __restrict__ W2L,
    const float* __restrict__ W1V, const float* __restrict__ W2V,
    float* __restrict__ W1LT, float* __restrict__ W2LT,
    float* __restrict__ W1VT, float* __restrict__ W2VT, int* __restrict__ viol)
{
  int t = blockIdx.x*256 + threadIdx.x;
  if (t < 4) viol[t] = 0;
  if (t < 1536){ int i = t/128, j = t%128; W1LT[t] = W1L[j*12+i]; W1VT[t] = W1V[j*12+i]; }
  if (t < 16384){ int i = t/128, j = t%128; W2LT[t] = W2L[j*128+i]; W2VT[t] = W2V[j*128+i]; }
}

// ---------------- per-stage state + batch viol reduction ----------------
__global__ void __launch_bounds__(256) k_pre(int stage,
    const float* __restrict__ obs, const float* __restrict__ kqd,
    float* __restrict__ q_cur, float* __restrict__ qd_cur, int* __restrict__ viol)
{
  int b = blockIdx.x*256 + threadIdx.x;
  if (b >= BATCH) return;
  const float* o = obs + b*12;
  unsigned mask = 0;
  #pragma unroll
  for (int i=0;i<6;i++){
    float q0 = o[i], qd0 = o[6+i];
    float q, qd;
    if (stage == 0){ q=q0; qd=qd0; }
    else if (stage == 1){
      q  = q0 + 0.5f*DT*qd0;
      qd = qd0 + 0.5f*DT*kqd[b*6+i];
    } else if (stage == 2){
      q  = q0 + 0.5f*DT*qd0 + 0.25f*DT*DT*kqd[b*6+i];
      qd = qd0 + 0.5f*DT*kqd[B6 + b*6+i];
    } else {
      q  = q0 + DT*qd0 + 0.5f*DT*DT*kqd[B6 + b*6+i];
      qd = qd0 + DT*kqd[2*B6 + b*6+i];
    }
    q_cur[b*6+i]=q; qd_cur[b*6+i]=qd;
    float lo = c_LOWER[i]+0.1f, up = c_UPPER[i]-0.1f;
    if (q <= lo || q >= up) mask |= (1u<<i);
  }
  unsigned wm = 0;
  #pragma unroll
  for (int i=0;i<6;i++) if (__ballot((int)((mask>>i)&1u))) wm |= (1u<<i);
  if ((threadIdx.x & 63)==0 && wm) atomicOr(viol + stage, (int)wm);
}

// ---------------- heavy per-stage accel ----------------
__global__ void __launch_bounds__(128) k_accel(
    const float* __restrict__ q_cur, const float* __restrict__ qd_cur,
    const float* __restrict__ action,
    const float* __restrict__ W1LT, const float* __restrict__ b1L,
    const float* __restrict__ W2LT, const float* __restrict__ b2L,
    const float* __restrict__ W3L,  const float* __restrict__ b3L,
    const float* __restrict__ W1VT, const float* __restrict__ b1V,
    const float* __restrict__ W2VT, const float* __restrict__ b2V,
    const float* __restrict__ W2V,  const float* __restrict__ W1V,
    const float* __restrict__ W3V,
    const int* __restrict__ viol_stage,
    float* __restrict__ kqd_out)
{
  __shared__ alignas(16) float sh_t[12][16];
  __shared__ alignas(16) float sh_A[128][16];
  __shared__ alignas(16) float sh_B[128][16];
  __shared__ alignas(16) float sh_s1[128][16];
  __shared__ alignas(16) float sh_s2[128][16];
  __shared__ alignas(16) float sh_y[21][16];
  __shared__ alignas(16) float sh_s3[21][16];
  __shared__ alignas(16) float sh_dy[21][16];   // reused as dV/dt after tangents
  __shared__ float sh_q[6][16], sh_qd[6][16], sh_tau[6][16], sh_f[6][16];
  __shared__ float sh_c[6][16], sh_grav[6][16], sh_v[6][16];

  const int tid = threadIdx.x;
  const int s0  = blockIdx.x * 16;
  const int vm  = *viol_stage;

  // ---- load tile, trig features, tau, constraint force
  if (tid < 96){
    int s = tid & 15, i = tid >> 4;
    float q  = q_cur [(s0+s)*6 + i];
    float qd = qd_cur[(s0+s)*6 + i];
    sh_q[i][s]=q; sh_qd[i][s]=qd;
    sh_tau[i][s] = action[(s0+s)*6+i] * c_EFFORT[i];
    sh_t[2*i][s]   = cosf(q);
    sh_t[2*i+1][s] = sinf(q);
    float lo = c_LOWER[i]+0.1f, up = c_UPPER[i]-0.1f;
    float barrier = -5.0f*(1.0f/(q-lo) - 1.0f/(up-q));
    float clip = (q<=lo)? c_EFFORT[i] : ((q>=up)? -c_EFFORT[i] : 0.0f);
    sh_f[i][s] = ((vm>>i)&1) ? clip : barrier;
    sh_c[i][s] = 0.0f;
  }
  __syncthreads();

  // ---- L-net layer 1
  {
    float bj = b1L[tid];
    float4 a0 = make_float4(bj,bj,bj,bj), a1=a0, a2=a0, a3=a0;
    #pragma unroll
    for (int i=0;i<12;i++){ float w = W1LT[i*128+tid]; fma16(w, sh_t[i], a0,a1,a2,a3); }
    act_store(sh_A[tid], sh_s1[tid], a0,a1,a2,a3);
  }
  __syncthreads();

  // ---- L-net layer 2
  {
    float bj = b2L[tid];
    float4 a0 = make_float4(bj,bj,bj,bj), a1=a0, a2=a0, a3=a0;
    #pragma unroll 4
    for (int i=0;i<128;i++){ float w = W2LT[i*128+tid]; fma16(w, sh_A[i], a0,a1,a2,a3); }
    act_store(sh_B[tid], sh_s2[tid], a0,a1,a2,a3);
  }
  __syncthreads();

  // ---- L-net layer 3 (21 outputs)
  for (int idx=tid; idx<336; idx+=128){
    int o = idx>>4, s = idx&15;
    float acc = b3L[o];
    const float* wr = W3L + o*128;
    #pragma unroll 4
    for (int i=0;i<128;i++) acc = fmaf(wr[i], sh_B[i][s], acc);
    sh_y[o][s]  = sp_f(acc);
    sh_s3[o][s] = sig_f(acc);
  }
  __syncthreads();

  // ---- v = L^T qdot
  if (tid < 96){
    int s = tid & 15, jj = tid >> 4;
    float acc = 0.f;
    for (int i=jj;i<6;i++) acc = fmaf(sh_y[c_ROWOFF[i]+jj][s], sh_qd[i][s], acc);
    sh_v[jj][s] = acc;
  }

  // ---- tangent loop: dM/dq_g, accumulate Coriolis c
  for (int g=0; g<6; ++g){
    __syncthreads();
    // dh1 = s1 * (cos*W1[:,2g+1] - sin*W1[:,2g])
    {
      float w0 = W1LT[(2*g)*128+tid];
      float w1 = W1LT[(2*g+1)*128+tid];
      const float4* pc = reinterpret_cast<const float4*>(sh_t[2*g]);
      const float4* psn= reinterpret_cast<const float4*>(sh_t[2*g+1]);
      const float4* p1 = reinterpret_cast<const float4*>(sh_s1[tid]);
      float4* pa = reinterpret_cast<float4*>(sh_A[tid]);
      #pragma unroll
      for (int k=0;k<4;k++){
        float4 tc=pc[k], tsn=psn[k], s1=p1[k], r;
        r.x = s1.x*(tc.x*w1 - tsn.x*w0);
        r.y = s1.y*(tc.y*w1 - tsn.y*w0);
        r.z = s1.z*(tc.z*w1 - tsn.z*w0);
        r.w = s1.w*(tc.w*w1 - tsn.w*w0);
        pa[k] = r;
      }
    }
    __syncthreads();
    // dh2 = s2 * (W2L dh1)
    {
      float4 a0 = make_float4(0.f,0.f,0.f,0.f), a1=a0, a2=a0, a3=a0;
      #pragma unroll 4
      for (int i=0;i<128;i++){ float w = W2LT[i*128+tid]; fma16(w, sh_A[i], a0,a1,a2,a3); }
      mulstore16(sh_s2[tid], sh_B[tid], a0,a1,a2,a3);
    }
    __syncthreads();
    // dy = s3 * (W3L dh2)
    for (int idx=tid; idx<336; idx+=128){
      int o = idx>>4, s = idx&15;
      float acc = 0.f;
      const float* wr = W3L + o*128;
      #pragma unroll 4
      for (int i=0;i<128;i++) acc = fmaf(wr[i], sh_B[i][s], acc);
      sh_dy[o][s] = sh_s3[o][s]*acc;
    }
    __syncthreads();
    // small per-sample: w_g = dL v + L u_g ; c += qd_g*w_g ; c_g -= 0.5 qd·w_g
    if (tid < 16){
      int s = tid;
      float qd[6];
      #pragma unroll
      for (int i=0;i<6;i++) qd[i] = sh_qd[i][s];
      float u[6];
      #pragma unroll
      for (int jj=0;jj<6;jj++){
        float acc = 0.f;
        for (int i=jj;i<6;i++) acc = fmaf(sh_dy[c_ROWOFF[i]+jj][s], qd[i], acc);
        u[jj] = acc;
      }
      float w[6]; float r = 0.f;
      #pragma unroll
      for (int i=0;i<6;i++){
        float acc = 0.f;
        for (int j=0;j<=i;j++){
          acc = fmaf(sh_dy[c_ROWOFF[i]+j][s], sh_v[j][s], acc);
          acc = fmaf(sh_y [c_ROWOFF[i]+j][s], u[j], acc);
        }
        w[i] = acc;
        r = fmaf(qd[i], acc, r);
      }
      float qg = qd[g];
      #pragma unroll
      for (int i=0;i<6;i++) sh_c[i][s] = fmaf(qg, w[i], sh_c[i][s]);
      sh_c[g][s] -= 0.5f*r;
    }
  }
  __syncthreads();

  // ---- V-net layer 1 (overwrites sh_A, sh_s1)
  {
    float bj = b1V[tid];
    float4 a0 = make_float4(bj,bj,bj,bj), a1=a0, a2=a0, a3=a0;
    #pragma unroll
    for (int i=0;i<12;i++){ float w = W1VT[i*128+tid]; fma16(w, sh_t[i], a0,a1,a2,a3); }
    act_store(sh_A[tid], sh_s1[tid], a0,a1,a2,a3);
  }
  __syncthreads();
  // ---- V-net layer 2: only need g2 = sigmoid(z2V) * W3V
  {
    float bj = b2V[tid];
    float4 a0 = make_float4(bj,bj,bj,bj), a1=a0, a2=a0, a3=a0;
    #pragma unroll 4
    for (int i=0;i<128;i++){ float w = W2VT[i*128+tid]; fma16(w, sh_A[i], a0,a1,a2,a3); }
    float w3 = W3V[tid];
    float4* pb = reinterpret_cast<float4*>(sh_B[tid]);
    pb[0] = make_float4(sig_f(a0.x)*w3, sig_f(a0.y)*w3, sig_f(a0.z)*w3, sig_f(a0.w)*w3);
    pb[1] = make_float4(sig_f(a1.x)*w3, sig_f(a1.y)*w3, sig_f(a1.z)*w3, sig_f(a1.w)*w3);
    pb[2] = make_float4(sig_f(a2.x)*w3, sig_f(a2.y)*w3, sig_f(a2.z)*w3, sig_f(a2.w)*w3);
    pb[3] = make_float4(sig_f(a3.x)*w3, sig_f(a3.y)*w3, sig_f(a3.z)*w3, sig_f(a3.w)*w3);
  }
  __syncthreads();
  // ---- V backward: g1 = s1V * (W2V^T g2)  (W2V original layout: coalesced over tid)
  {
    float4 a0 = make_float4(0.f,0.f,0.f,0.f), a1=a0, a2=a0, a3=a0;
    #pragma unroll 4
    for (int j=0;j<128;j++){ float w = W2V[j*128+tid]; fma16(w, sh_B[j], a0,a1,a2,a3); }
    mulstore16(sh_s1[tid], sh_A[tid], a0,a1,a2,a3);
  }
  __syncthreads();
  // ---- dV/dt = W1V^T g1  (12 outputs)
  {
    float (*sh_dV)[16] = sh_dy;
    for (int idx=tid; idx<192; idx+=128){
      int i2 = idx>>4, s = idx&15;
      float acc = 0.f;
      #pragma unroll 4
      for (int j=0;j<128;j++) acc = fmaf(W1V[j*12+i2], sh_A[j][s], acc);
      sh_dV[i2][s] = acc;
    }
  }
  __syncthreads();
  // ---- gravity: chain through trig
  {
    float (*sh_dV)[16] = sh_dy;
    if (tid < 96){
      int k = tid>>4, s = tid&15;
      sh_grav[k][s] = fmaf(sh_t[2*k][s], sh_dV[2*k+1][s], -(sh_t[2*k+1][s]*sh_dV[2*k][s]));
    }
  }
  __syncthreads();

  // ---- assembly: rhs, two triangular solves with L (M = L L^T), write accel
  if (tid < 16){
    int s = tid;
    float Lm[21];
    #pragma unroll
    for (int o=0;o<21;o++) Lm[o] = sh_y[o][s];
    float rhs[6];
    #pragma unroll
    for (int i=0;i<6;i++) rhs[i] = sh_tau[i][s] - sh_c[i][s] - sh_grav[i][s] - sh_f[i][s];
    float z[6];
    #pragma unroll
    for (int i=0;i<6;i++){
      float acc = rhs[i];
      for (int j=0;j<i;j++) acc = fmaf(-Lm[c_ROWOFF[i]+j], z[j], acc);
      z[i] = acc / Lm[c_ROWOFF[i]+i];
    }
    float a[6];
    #pragma unroll
    for (int i=5;i>=0;i--){
      float acc = z[i];
      for (int j=i+1;j<6;j++) acc = fmaf(-Lm[c_ROWOFF[j]+i], a[j], acc);
      a[i] = acc / Lm[c_ROWOFF[i]+i];
    }
    #pragma unroll
    for (int i=0;i<6;i++) kqd_out[(s0+s)*6+i] = a[i];
  }
}

// ---------------- final RK4 combine ----------------
__global__ void __launch_bounds__(256) k_final(const float* __restrict__ obs,
    const float* __restrict__ kqd, float* __restrict__ out)
{
  int b = blockIdx.x*256 + threadIdx.x;
  if (b >= BATCH) return;
  const float* o = obs + b*12;
  float* po = out + b*12;
  #pragma unroll
  for (int i=0;i<6;i++){
    float q0=o[i], qd0=o[6+i];
    float k1=kqd[b*6+i], k2=kqd[B6+b*6+i], k3=kqd[2*B6+b*6+i], k4=kqd[3*B6+b*6+i];
    float qn = q0 + DT*qd0 + (DT*DT/6.0f)*(k1+k2+k3);
    qn = fminf(fmaxf(qn, c_LOWER[i]), c_UPPER[i]);
    po[i] = qn;
    po[6+i] = qd0 + (DT/6.0f)*(k1 + 2.0f*k2 + 2.0f*k3 + k4);
  }
}

extern "C" void kernel_launch(void* const* d_in, const int* in_sizes, int n_in,
                              void* d_out, int out_size, void* d_ws, size_t ws_size,
                              hipStream_t stream) {
  const float* obs    = (const float*)d_in[0];
  const float* action = (const float*)d_in[1];
  const float* W1L = (const float*)d_in[2];  const float* b1L = (const float*)d_in[3];
  const float* W2L = (const float*)d_in[4];  const float* b2L = (const float*)d_in[5];
  const float* W3L = (const float*)d_in[6];  const float* b3L = (const float*)d_in[7];
  const float* W1V = (const float*)d_in[8];  const float* b1V = (const float*)d_in[9];
  const float* W2V = (const float*)d_in[10]; const float* b2V = (const float*)d_in[11];
  const float* W3V = (const float*)d_in[12]; // b3V (d_in[13]) unused: only grad of V needed

  float* ws = (float*)d_ws;
  float* W2LT = ws;               // 16384
  float* W2VT = W2LT + 16384;     // 16384
  float* W1LT = W2VT + 16384;     // 1536
  float* W1VT = W1LT + 1536;      // 1536
  float* q_cur  = W1VT + 1536;    // B6
  float* qd_cur = q_cur + B6;     // B6
  float* kqd    = qd_cur + B6;    // 4*B6
  int*   viol   = (int*)(kqd + 4*B6);

  float* out = (float*)d_out;

  k_init<<<64,256,0,stream>>>(W1L,W2L,W1V,W2V,W1LT,W2LT,W1VT,W2VT,viol);
  for (int s=0; s<4; ++s){
    k_pre<<<64,256,0,stream>>>(s, obs, kqd, q_cur, qd_cur, viol);
    k_accel<<<1024,128,0,stream>>>(q_cur, qd_cur, action,
        W1LT, b1L, W2LT, b2L, W3L, b3L,
        W1VT, b1V, W2VT, b2V, W2V, W1V, W3V,
        viol + s, kqd + s*B6);
  }
  k_final<<<64,256,0,stream>>>(obs, kqd, out);
}

// Round 2
// 684.340 us; speedup vs baseline: 1.1430x; 1.1430x over previous
//
#include <hip/hip_runtime.h>
#include <math.h>

#define BATCH 16384
#define B6 (BATCH*6)
#define DT 0.01f

__device__ __constant__ float c_LOWER[6]  = {-6.28f,-6.28f,-3.14f,-6.28f,-6.28f,-6.28f};
__device__ __constant__ float c_UPPER[6]  = { 6.28f, 6.28f, 3.14f, 6.28f, 6.28f, 6.28f};
__device__ __constant__ float c_EFFORT[6] = {150.0f,150.0f,150.0f,28.0f,28.0f,28.0f};
__device__ __constant__ int   c_ROWOFF[6] = {0,1,3,6,10,15};

__device__ __forceinline__ float sp_f(float z){ return fmaxf(z,0.0f) + log1pf(expf(-fabsf(z))); }
__device__ __forceinline__ float sig_f(float z){ return 1.0f/(1.0f+expf(-z)); }

__device__ __forceinline__ float4 f4all(float v){ return make_float4(v,v,v,v); }
__device__ __forceinline__ void fma4(float4& acc, float w, float4 a){
  acc.x=fmaf(w,a.x,acc.x); acc.y=fmaf(w,a.y,acc.y); acc.z=fmaf(w,a.z,acc.z); acc.w=fmaf(w,a.w,acc.w);
}
__device__ __forceinline__ float4 mul4(float4 a, float4 b){
  return make_float4(a.x*b.x, a.y*b.y, a.z*b.z, a.w*b.w);
}
__device__ __forceinline__ float4 sp4(float4 z){
  return make_float4(sp_f(z.x),sp_f(z.y),sp_f(z.z),sp_f(z.w));
}
__device__ __forceinline__ float4 sig4(float4 z){
  return make_float4(sig_f(z.x),sig_f(z.y),sig_f(z.z),sig_f(z.w));
}

// 4 neurons (4*ng..+3) x 4 samples (s4..+3) GEMV tile over NI inputs.
// Wt layout: [NI][128] (transposed); src: LDS [NI][16].
template<int NI>
__device__ __forceinline__ void gemv_tile(const float* __restrict__ Wt,
                                          const float (*__restrict__ src)[16],
                                          int ng, int s4, float4 acc[4]){
  const float4* W4 = reinterpret_cast<const float4*>(Wt);
  #pragma unroll 4
  for (int i=0;i<NI;i++){
    float4 w = W4[i*32+ng];
    float4 a = *reinterpret_cast<const float4*>(&src[i][s4]);
    fma4(acc[0], w.x, a); fma4(acc[1], w.y, a); fma4(acc[2], w.z, a); fma4(acc[3], w.w, a);
  }
}

// ---------------- init: transpose weights, zero viol ----------------
__global__ void __launch_bounds__(256) k_init(
    const float* __restrict__ W1L, const float* __restrict__ W2L,
    const float* __restrict__ W1V, const float* __restrict__ W2V,
    const float* __restrict__ W3L,
    float* __restrict__ W1LT, float* __restrict__ W2LT,
    float* __restrict__ W1VT, float* __restrict__ W2VT,
    float* __restrict__ W3LT, int* __restrict__ viol)
{
  int t = blockIdx.x*256 + threadIdx.x;
  if (t < 4) viol[t] = 0;
  if (t < 1536){ int i = t/128, j = t%128; W1LT[t] = W1L[j*12+i]; W1VT[t] = W1V[j*12+i]; }
  if (t < 2688){ int i = t/21, o = t%21; W3LT[t] = W3L[o*128+i]; }
  if (t < 16384){ int i = t/128, j = t%128; W2LT[t] = W2L[j*128+i]; W2VT[t] = W2V[j*128+i]; }
}

// ---------------- per-stage state + batch viol reduction ----------------
__global__ void __launch_bounds__(256) k_pre(int stage,
    const float* __restrict__ obs, const float* __restrict__ kqd,
    float* __restrict__ q_cur, float* __restrict__ qd_cur, int* __restrict__ viol)
{
  int b = blockIdx.x*256 + threadIdx.x;
  if (b >= BATCH) return;
  const float* o = obs + b*12;
  unsigned mask = 0;
  #pragma unroll
  for (int i=0;i<6;i++){
    float q0 = o[i], qd0 = o[6+i];
    float q, qd;
    if (stage == 0){ q=q0; qd=qd0; }
    else if (stage == 1){
      q  = q0 + 0.5f*DT*qd0;
      qd = qd0 + 0.5f*DT*kqd[b*6+i];
    } else if (stage == 2){
      q  = q0 + 0.5f*DT*qd0 + 0.25f*DT*DT*kqd[b*6+i];
      qd = qd0 + 0.5f*DT*kqd[B6 + b*6+i];
    } else {
      q  = q0 + DT*qd0 + 0.5f*DT*DT*kqd[B6 + b*6+i];
      qd = qd0 + DT*kqd[2*B6 + b*6+i];
    }
    q_cur[b*6+i]=q; qd_cur[b*6+i]=qd;
    float lo = c_LOWER[i]+0.1f, up = c_UPPER[i]-0.1f;
    if (q <= lo || q >= up) mask |= (1u<<i);
  }
  unsigned wm = 0;
  #pragma unroll
  for (int i=0;i<6;i++) if (__ballot((int)((mask>>i)&1u))) wm |= (1u<<i);
  if ((threadIdx.x & 63)==0 && wm) atomicOr(viol + stage, (int)wm);
}

// ---------------- heavy per-stage accel ----------------
// 16 samples/block, 128 threads: thread = (ng = tid&31 -> neurons 4ng..4ng+3,
// sg = tid>>5 -> samples 4sg..4sg+3). Sigmoid tiles live in registers.
__global__ void __launch_bounds__(128) k_accel(
    const float* __restrict__ q_cur, const float* __restrict__ qd_cur,
    const float* __restrict__ action,
    const float* __restrict__ W1LT, const float* __restrict__ b1L,
    const float* __restrict__ W2LT, const float* __restrict__ b2L,
    const float* __restrict__ W3LT, const float* __restrict__ b3L,
    const float* __restrict__ W1VT, const float* __restrict__ b1V,
    const float* __restrict__ W2VT, const float* __restrict__ b2V,
    const float* __restrict__ W2V,  const float* __restrict__ W1V,
    const float* __restrict__ W3V,
    const int* __restrict__ viol_stage,
    float* __restrict__ kqd_out)
{
  __shared__ alignas(16) float sh_t[12][16];
  __shared__ alignas(16) float sh_A[128][16];
  __shared__ alignas(16) float sh_B[128][16];
  __shared__ alignas(16) float sh_y[21][16];
  __shared__ alignas(16) float sh_dy[21][16];
  __shared__ float sh_qd[6][16], sh_tau[6][16], sh_f[6][16];
  __shared__ float sh_c[6][16], sh_grav[6][16], sh_v[6][16];

  const int tid = threadIdx.x;
  const int ng  = tid & 31;
  const int sg  = tid >> 5;
  const int s4  = sg << 2;
  const int s0  = blockIdx.x * 16;
  const int vm  = *viol_stage;

  // ---- load tile, trig features, tau, constraint force
  if (tid < 96){
    int s = tid & 15, i = tid >> 4;
    float q  = q_cur [(s0+s)*6 + i];
    float qd = qd_cur[(s0+s)*6 + i];
    sh_qd[i][s]=qd;
    sh_tau[i][s] = action[(s0+s)*6+i] * c_EFFORT[i];
    sh_t[2*i][s]   = cosf(q);
    sh_t[2*i+1][s] = sinf(q);
    float lo = c_LOWER[i]+0.1f, up = c_UPPER[i]-0.1f;
    float barrier = -5.0f*(1.0f/(q-lo) - 1.0f/(up-q));
    float clip = (q<=lo)? c_EFFORT[i] : ((q>=up)? -c_EFFORT[i] : 0.0f);
    sh_f[i][s] = ((vm>>i)&1) ? clip : barrier;
    sh_c[i][s] = 0.0f;
  }
  __syncthreads();

  float4 s1t[4], s2t[4];

  // ---- L-net layer 1
  {
    float4 b4 = reinterpret_cast<const float4*>(b1L)[ng];
    float4 acc[4] = { f4all(b4.x), f4all(b4.y), f4all(b4.z), f4all(b4.w) };
    gemv_tile<12>(W1LT, sh_t, ng, s4, acc);
    #pragma unroll
    for (int r=0;r<4;r++){
      *reinterpret_cast<float4*>(&sh_A[4*ng+r][s4]) = sp4(acc[r]);
      s1t[r] = sig4(acc[r]);
    }
  }
  __syncthreads();

  // ---- L-net layer 2
  {
    float4 b4 = reinterpret_cast<const float4*>(b2L)[ng];
    float4 acc[4] = { f4all(b4.x), f4all(b4.y), f4all(b4.z), f4all(b4.w) };
    gemv_tile<128>(W2LT, sh_A, ng, s4, acc);
    #pragma unroll
    for (int r=0;r<4;r++){
      *reinterpret_cast<float4*>(&sh_B[4*ng+r][s4]) = sp4(acc[r]);
      s2t[r] = sig4(acc[r]);
    }
  }
  __syncthreads();

  // ---- L-net layer 3 (21 outputs): thread (o=ng<21, sg)
  float4 s3t = f4all(0.f);
  if (ng < 21){
    float4 acc = f4all(b3L[ng]);
    #pragma unroll 4
    for (int i=0;i<128;i++){
      float w = W3LT[i*21+ng];
      float4 a = *reinterpret_cast<const float4*>(&sh_B[i][s4]);
      fma4(acc, w, a);
    }
    *reinterpret_cast<float4*>(&sh_y[ng][s4]) = sp4(acc);
    s3t = sig4(acc);
  }
  __syncthreads();

  // ---- v = L^T qdot
  if (tid < 96){
    int s = tid & 15, jj = tid >> 4;
    float acc = 0.f;
    for (int i=jj;i<6;i++) acc = fmaf(sh_y[c_ROWOFF[i]+jj][s], sh_qd[i][s], acc);
    sh_v[jj][s] = acc;
  }

  // ---- tangent loop over g: dM/dq_g, accumulate Coriolis c
  for (int g=0; g<6; ++g){
    __syncthreads();
    // dh1 = s1 * (cos*W1[:,2g+1] - sin*W1[:,2g])  -> sh_A
    {
      float4 w0 = reinterpret_cast<const float4*>(W1LT + (2*g)*128)[ng];
      float4 w1 = reinterpret_cast<const float4*>(W1LT + (2*g+1)*128)[ng];
      float4 tc = *reinterpret_cast<const float4*>(&sh_t[2*g][s4]);
      float4 ts = *reinterpret_cast<const float4*>(&sh_t[2*g+1][s4]);
      float wr0[4] = {w0.x,w0.y,w0.z,w0.w};
      float wr1[4] = {w1.x,w1.y,w1.z,w1.w};
      #pragma unroll
      for (int r=0;r<4;r++){
        float4 d;
        d.x = s1t[r].x*(tc.x*wr1[r] - ts.x*wr0[r]);
        d.y = s1t[r].y*(tc.y*wr1[r] - ts.y*wr0[r]);
        d.z = s1t[r].z*(tc.z*wr1[r] - ts.z*wr0[r]);
        d.w = s1t[r].w*(tc.w*wr1[r] - ts.w*wr0[r]);
        *reinterpret_cast<float4*>(&sh_A[4*ng+r][s4]) = d;
      }
    }
    __syncthreads();
    // dh2 = s2 * (W2L dh1) -> sh_B
    {
      float4 acc[4] = { f4all(0.f), f4all(0.f), f4all(0.f), f4all(0.f) };
      gemv_tile<128>(W2LT, sh_A, ng, s4, acc);
      #pragma unroll
      for (int r=0;r<4;r++)
        *reinterpret_cast<float4*>(&sh_B[4*ng+r][s4]) = mul4(s2t[r], acc[r]);
    }
    __syncthreads();
    // dy = s3 * (W3L dh2) -> sh_dy
    if (ng < 21){
      float4 acc = f4all(0.f);
      #pragma unroll 4
      for (int i=0;i<128;i++){
        float w = W3LT[i*21+ng];
        float4 a = *reinterpret_cast<const float4*>(&sh_B[i][s4]);
        fma4(acc, w, a);
      }
      *reinterpret_cast<float4*>(&sh_dy[ng][s4]) = mul4(s3t, acc);
    }
    __syncthreads();
    // small per-sample: w_g = dL v + L u_g ; split 8 samples per wave
    if ((tid & 63) < 8){
      int s = ((tid >> 6) << 3) | (tid & 7);
      float qd[6];
      #pragma unroll
      for (int i=0;i<6;i++) qd[i] = sh_qd[i][s];
      float u[6];
      #pragma unroll
      for (int jj=0;jj<6;jj++){
        float acc = 0.f;
        for (int i=jj;i<6;i++) acc = fmaf(sh_dy[c_ROWOFF[i]+jj][s], qd[i], acc);
        u[jj] = acc;
      }
      float w[6]; float r = 0.f;
      #pragma unroll
      for (int i=0;i<6;i++){
        float acc = 0.f;
        for (int j=0;j<=i;j++){
          acc = fmaf(sh_dy[c_ROWOFF[i]+j][s], sh_v[j][s], acc);
          acc = fmaf(sh_y [c_ROWOFF[i]+j][s], u[j], acc);
        }
        w[i] = acc;
        r = fmaf(qd[i], acc, r);
      }
      float qg = qd[g];
      #pragma unroll
      for (int i=0;i<6;i++) sh_c[i][s] = fmaf(qg, w[i], sh_c[i][s]);
      sh_c[g][s] -= 0.5f*r;
    }
  }
  __syncthreads();

  // ---- V-net layer 1 -> sh_A, s1t (reused)
  {
    float4 b4 = reinterpret_cast<const float4*>(b1V)[ng];
    float4 acc[4] = { f4all(b4.x), f4all(b4.y), f4all(b4.z), f4all(b4.w) };
    gemv_tile<12>(W1VT, sh_t, ng, s4, acc);
    #pragma unroll
    for (int r=0;r<4;r++){
      *reinterpret_cast<float4*>(&sh_A[4*ng+r][s4]) = sp4(acc[r]);
      s1t[r] = sig4(acc[r]);
    }
  }
  __syncthreads();
  // ---- V layer 2: g2 = sigmoid(z2V) * W3V -> sh_B
  {
    float4 b4 = reinterpret_cast<const float4*>(b2V)[ng];
    float4 acc[4] = { f4all(b4.x), f4all(b4.y), f4all(b4.z), f4all(b4.w) };
    gemv_tile<128>(W2VT, sh_A, ng, s4, acc);
    float4 w3 = reinterpret_cast<const float4*>(W3V)[ng];
    float wr[4] = {w3.x,w3.y,w3.z,w3.w};
    #pragma unroll
    for (int r=0;r<4;r++){
      float4 g2 = sig4(acc[r]);
      *reinterpret_cast<float4*>(&sh_B[4*ng+r][s4]) =
        make_float4(g2.x*wr[r], g2.y*wr[r], g2.z*wr[r], g2.w*wr[r]);
    }
  }
  __syncthreads();
  // ---- V backward: g1 = s1V * (W2V^T g2) -> sh_A (W2V original layout is the transpose)
  {
    float4 acc[4] = { f4all(0.f), f4all(0.f), f4all(0.f), f4all(0.f) };
    gemv_tile<128>(W2V, sh_B, ng, s4, acc);
    #pragma unroll
    for (int r=0;r<4;r++)
      *reinterpret_cast<float4*>(&sh_A[4*ng+r][s4]) = mul4(s1t[r], acc[r]);
  }
  __syncthreads();
  // ---- dV/dt = W1V^T g1 (12 outputs) -> sh_dy rows 0..11
  if (ng < 12){
    float4 acc = f4all(0.f);
    #pragma unroll 4
    for (int j=0;j<128;j++){
      float w = W1V[j*12+ng];
      float4 a = *reinterpret_cast<const float4*>(&sh_A[j][s4]);
      fma4(acc, w, a);
    }
    *reinterpret_cast<float4*>(&sh_dy[ng][s4]) = acc;
  }
  __syncthreads();
  // ---- gravity: chain through trig
  if (tid < 96){
    int k = tid>>4, s = tid&15;
    sh_grav[k][s] = fmaf(sh_t[2*k][s], sh_dy[2*k+1][s], -(sh_t[2*k+1][s]*sh_dy[2*k][s]));
  }
  __syncthreads();

  // ---- assembly: rhs, two triangular solves with L (M = L L^T); 8 samples/wave
  if ((tid & 63) < 8){
    int s = ((tid >> 6) << 3) | (tid & 7);
    float Lm[21];
    #pragma unroll
    for (int o=0;o<21;o++) Lm[o] = sh_y[o][s];
    float rhs[6];
    #pragma unroll
    for (int i=0;i<6;i++) rhs[i] = sh_tau[i][s] - sh_c[i][s] - sh_grav[i][s] - sh_f[i][s];
    float z[6];
    #pragma unroll
    for (int i=0;i<6;i++){
      float acc = rhs[i];
      for (int j=0;j<i;j++) acc = fmaf(-Lm[c_ROWOFF[i]+j], z[j], acc);
      z[i] = acc / Lm[c_ROWOFF[i]+i];
    }
    float a[6];
    #pragma unroll
    for (int i=5;i>=0;i--){
      float acc = z[i];
      for (int j=i+1;j<6;j++) acc = fmaf(-Lm[c_ROWOFF[j]+i], a[j], acc);
      a[i] = acc / Lm[c_ROWOFF[i]+i];
    }
    #pragma unroll
    for (int i=0;i<6;i++) kqd_out[(s0+s)*6+i] = a[i];
  }
}

// ---------------- final RK4 combine ----------------
__global__ void __launch_bounds__(256) k_final(const float* __restrict__ obs,
    const float* __restrict__ kqd, float* __restrict__ out)
{
  int b = blockIdx.x*256 + threadIdx.x;
  if (b >= BATCH) return;
  const float* o = obs + b*12;
  float* po = out + b*12;
  #pragma unroll
  for (int i=0;i<6;i++){
    float q0=o[i], qd0=o[6+i];
    float k1=kqd[b*6+i], k2=kqd[B6+b*6+i], k3=kqd[2*B6+b*6+i], k4=kqd[3*B6+b*6+i];
    float qn = q0 + DT*qd0 + (DT*DT/6.0f)*(k1+k2+k3);
    qn = fminf(fmaxf(qn, c_LOWER[i]), c_UPPER[i]);
    po[i] = qn;
    po[6+i] = qd0 + (DT/6.0f)*(k1 + 2.0f*k2 + 2.0f*k3 + k4);
  }
}

extern "C" void kernel_launch(void* const* d_in, const int* in_sizes, int n_in,
                              void* d_out, int out_size, void* d_ws, size_t ws_size,
                              hipStream_t stream) {
  const float* obs    = (const float*)d_in[0];
  const float* action = (const float*)d_in[1];
  const float* W1L = (const float*)d_in[2];  const float* b1L = (const float*)d_in[3];
  const float* W2L = (const float*)d_in[4];  const float* b2L = (const float*)d_in[5];
  const float* W3L = (const float*)d_in[6];  const float* b3L = (const float*)d_in[7];
  const float* W1V = (const float*)d_in[8];  const float* b1V = (const float*)d_in[9];
  const float* W2V = (const float*)d_in[10]; const float* b2V = (const float*)d_in[11];
  const float* W3V = (const float*)d_in[12]; // b3V (d_in[13]) unused: only grad of V needed

  float* ws = (float*)d_ws;
  float* W2LT = ws;               // 16384
  float* W2VT = W2LT + 16384;     // 16384
  float* W1LT = W2VT + 16384;     // 1536
  float* W1VT = W1LT + 1536;      // 1536
  float* W3LT = W1VT + 1536;      // 2688
  float* q_cur  = W3LT + 2688;    // B6
  float* qd_cur = q_cur + B6;     // B6
  float* kqd    = qd_cur + B6;    // 4*B6
  int*   viol   = (int*)(kqd + 4*B6);

  float* out = (float*)d_out;

  k_init<<<64,256,0,stream>>>(W1L,W2L,W1V,W2V,W3L,W1LT,W2LT,W1VT,W2VT,W3LT,viol);
  for (int s=0; s<4; ++s){
    k_pre<<<64,256,0,stream>>>(s, obs, kqd, q_cur, qd_cur, viol);
    k_accel<<<1024,128,0,stream>>>(q_cur, qd_cur, action,
        W1LT, b1L, W2LT, b2L, W3LT, b3L,
        W1VT, b1V, W2VT, b2V, W2V, W1V, W3V,
        viol + s, kqd + s*B6);
  }
  k_final<<<64,256,0,stream>>>(obs, kqd, out);
}